// Round 8
// baseline (2062.461 us; speedup 1.0000x reference)
//
#include <hip/hip_runtime.h>
#include <hip/hip_bf16.h>

#define VOCAB 10000
#define D 200
#define NLAYERS 3
#define NB 16
#define NS 512
#define M 8192        // NB*NS
#define KA 224        // padded K for A (h3 bf16), 7 * 32
#define KB 232        // padded K for fc_w bf16; 29 16B-chunks (odd -> no LDS bank conflicts)
#define NPADA 10120   // 79*128 = 10112, +8 rows slack for unguarded staging
#define NTILES_N 79
#define WKP 224       // padded K for w_hh f16 fragments (7*32)
#define WRP 208       // padded rows for w_hh (13*16)
#define HSTR 232      // LDS H stride in f16 (16B-chunk odd count)

typedef __bf16 bf16x8 __attribute__((ext_vector_type(8)));
typedef _Float16 f16x8 __attribute__((ext_vector_type(8)));
typedef _Float16 f16x4 __attribute__((ext_vector_type(4)));
typedef float  f32x4  __attribute__((ext_vector_type(4)));
typedef unsigned int u32x4 __attribute__((ext_vector_type(4)));

// ---------------- embedding gather: h0[bs][d] = emb[x[bs]][d] ----------------
__global__ void k_embed(const int* __restrict__ x, const float* __restrict__ emb,
                        float* __restrict__ h0) {
    int i = blockIdx.x * blockDim.x + threadIdx.x;
    if (i < M * D) {
        int bs = i / D;
        int d  = i - bs * D;
        h0[i] = emb[(size_t)x[bs] * D + d];
    }
}

// ---------------- transpose w_ih: wt[l][k][n] = w_ih[l][n][k] ----------------
__global__ void k_wtrans(const float* __restrict__ w_ih, float* __restrict__ wt) {
    int i = blockIdx.x * blockDim.x + threadIdx.x;
    if (i < NLAYERS * D * D) {
        int l = i / (D * D);
        int r = i - l * D * D;
        int k = r / D;
        int n = r - k * D;
        wt[i] = w_ih[l * D * D + n * D + k];
    }
}

// ---------------- w_hh -> f16 padded [NLAYERS][WRP][WKP] ----------------
__global__ void k_whf(const float* __restrict__ w_hh, _Float16* __restrict__ whf) {
    int i = blockIdx.x * blockDim.x + threadIdx.x;
    if (i < NLAYERS * WRP * WKP) {
        int l = i / (WRP * WKP);
        int r = (i / WKP) % WRP;
        int k = i % WKP;
        float v = (r < D && k < D) ? w_hh[l * D * D + r * D + k] : 0.f;
        whf[i] = (_Float16)v;
    }
}

// ---------------- fc_w -> bf16, padded [NPADA][KB] ----------------
__global__ void k_fcwbf(const float* __restrict__ fc_w, __bf16* __restrict__ fwb) {
    int i = blockIdx.x * blockDim.x + threadIdx.x;
    if (i < NPADA * KB) {
        int n = i / KB;
        int k = i - n * KB;
        float v = (n < VOCAB && k < D) ? fc_w[(size_t)n * D + k] : 0.f;
        fwb[i] = (__bf16)v;
    }
}

// ---------------- h3 -> bf16, padded [M][KA] ----------------
__global__ void k_hbf2(const float* __restrict__ h, __bf16* __restrict__ hbf) {
    int i = blockIdx.x * blockDim.x + threadIdx.x;
    if (i < M * KA) {
        int m = i / KA;
        int k = i - m * KA;
        float v = (k < D) ? h[(size_t)m * D + k] : 0.f;
        hbf[i] = (__bf16)v;
    }
}

// ---------------- xw = h @ w_ih^T + b_ih + b_hh  (f32) ----------------
__global__ void k_xw(const float* __restrict__ hin, const float* __restrict__ wt,
                     const float* __restrict__ b_ih, const float* __restrict__ b_hh,
                     float* __restrict__ xw) {
    int m0 = blockIdx.x * 32;
    int n  = threadIdx.x;
    if (n >= D) return;
    float bias = b_ih[n] + b_hh[n];
    for (int g = 0; g < 8; ++g) {
        const float* r0 = hin + (size_t)(m0 + g * 4) * D;
        float a0 = bias, a1 = bias, a2 = bias, a3 = bias;
        for (int k = 0; k < D; k += 4) {
            #pragma unroll
            for (int kk = 0; kk < 4; ++kk) {
                float w = wt[(k + kk) * D + n];      // coalesced, L2-resident
                float h0v = r0[k + kk];              // wave-uniform
                float h1v = r0[D + k + kk];
                float h2v = r0[2 * D + k + kk];
                float h3v = r0[3 * D + k + kk];
                a0 += h0v * w; a1 += h1v * w; a2 += h2v * w; a3 += h3v * w;
            }
        }
        size_t o = (size_t)(m0 + g * 4) * D + n;
        xw[o] = a0; xw[o + D] = a1; xw[o + 2 * D] = a2; xw[o + 3 * D] = a3;
    }
}

// ---------------- MFMA recurrent scan: ONE block, all 16 batch rows ---------
// Per step: C[208 rows x 16 batch] = W(208x224 f16) * H^T(224x16 f16), then
// h_new = tanh(xw + C). 448 threads = 7 waves; wave w owns row-tiles 2w,2w+1
// (13 real tiles). Weights stay in registers as A-fragments for the whole
// scan (MFMA reads them from VGPR/AGPR natively - demotion harmless). H is
// f16 in LDS, double-buffered, ONE barrier per step. Fragment access pattern
// is identical to the verified k_fc: A row-major [row][k], B row-major
// [col=batch][k], C col=lane&15, row=(lane>>4)*4+reg.
// Rationale (r7 post-mortem): the 16-CU f32 VALU scan was latency+issue bound
// at ~1205 cyc/step; batch=16 is exactly MFMA's N -> 91 mfma/step on 1 CU,
// VALU work collapses to ~8 tanh/lane.
__device__ inline float fast_tanh(float x) {
    x = fminf(fmaxf(x, -15.f), 15.f);
    float e = __expf(2.f * x);
    return (e - 1.f) / (e + 1.f);
}

__global__ __attribute__((amdgpu_flat_work_group_size(448, 448)))
void k_scan_m(const _Float16* __restrict__ whf,   // this layer, [WRP][WKP]
              float* __restrict__ io,             // xw in / h out, [NB][NS][D]
              float* __restrict__ hidden) {       // [NB][D]
    __shared__ _Float16 Hb[2][16][HSTR];
    const int t    = threadIdx.x;
    const int wid  = t >> 6;
    const int lane = t & 63;
    const int lr   = lane & 15;        // A row-in-tile / B batch col / C col
    const int lq   = lane >> 4;        // k-oct selector / C row group
    const int t0   = 2 * wid, t1 = 2 * wid + 1;
    const bool has1 = (t1 < 13);       // wave 6 has only tile 12

    // zero both H buffers (pad rows/cols stay zero forever; W pad also zero)
    for (int i = t; i < 2 * 16 * HSTR; i += 448) ((_Float16*)Hb)[i] = (_Float16)0.f;

    // load A-fragments (weights) once: af[t][ks] = W[t*16+lr][ks*32+lq*8 ..+8]
    f16x8 a0[7], a1[7];
    #pragma unroll
    for (int ks = 0; ks < 7; ++ks) {
        a0[ks] = *(const f16x8*)(whf + (size_t)(t0 * 16 + lr) * WKP + ks * 32 + lq * 8);
        if (has1)
            a1[ks] = *(const f16x8*)(whf + (size_t)(t1 * 16 + lr) * WKP + ks * 32 + lq * 8);
    }

    // output row bases for this lane's C fragments
    const int rb0 = t0 * 16 + lq * 4;
    const int rb1 = t1 * 16 + lq * 4;
    const bool st0 = (rb0 + 3 < D);               // all 4 rows real
    const bool st1 = has1 && (rb1 + 3 < D);
    const int rb0c = st0 ? rb0 : 0;               // clamped: loads never OOB
    const int rb1c = st1 ? rb1 : 0;

    const float* xb = io + (size_t)lr * NS * D;   // this lane's batch row
    f32x4 xw0 = *(const f32x4*)(xb + rb0c);       // prefetch s=0
    f32x4 xw1 = *(const f32x4*)(xb + rb1c);

    __syncthreads();

    int cur = 0;
    f32x4 o0{0.f,0.f,0.f,0.f}, o1{0.f,0.f,0.f,0.f};
    #pragma unroll 1
    for (int s = 0; s < NS; ++s) {
        // prefetch xw for s+1 (hidden under the mfma chain)
        const int sn = (s + 1 < NS) ? s + 1 : NS - 1;
        f32x4 nxw0 = *(const f32x4*)(xb + (size_t)sn * D + rb0c);
        f32x4 nxw1 = *(const f32x4*)(xb + (size_t)sn * D + rb1c);

        f32x4 acc0{0.f,0.f,0.f,0.f}, acc1{0.f,0.f,0.f,0.f};
        #pragma unroll
        for (int ks = 0; ks < 7; ++ks) {
            f16x8 b = *(const f16x8*)(&Hb[cur][lr][ks * 32 + lq * 8]);
            acc0 = __builtin_amdgcn_mfma_f32_16x16x32_f16(a0[ks], b, acc0, 0, 0, 0);
            if (has1)
                acc1 = __builtin_amdgcn_mfma_f32_16x16x32_f16(a1[ks], b, acc1, 0, 0, 0);
        }
        #pragma unroll
        for (int r = 0; r < 4; ++r) {
            o0[r] = fast_tanh(xw0[r] + acc0[r]);
            o1[r] = fast_tanh(xw1[r] + acc1[r]);
        }
        xw0 = nxw0; xw1 = nxw1;

        const int nxt = cur ^ 1;
        if (st0) {
            f16x4 hv; hv[0]=(_Float16)o0[0]; hv[1]=(_Float16)o0[1];
                      hv[2]=(_Float16)o0[2]; hv[3]=(_Float16)o0[3];
            *(f16x4*)(&Hb[nxt][lr][rb0]) = hv;                    // ds_write_b64
            *(f32x4*)(io + ((size_t)lr * NS + s) * D + rb0) = o0; // h out (f32)
        }
        if (st1) {
            f16x4 hv; hv[0]=(_Float16)o1[0]; hv[1]=(_Float16)o1[1];
                      hv[2]=(_Float16)o1[2]; hv[3]=(_Float16)o1[3];
            *(f16x4*)(&Hb[nxt][lr][rb1]) = hv;
            *(f32x4*)(io + ((size_t)lr * NS + s) * D + rb1) = o1;
        }
        __syncthreads();
        cur = nxt;
    }
    if (st0) *(f32x4*)(hidden + (size_t)lr * D + rb0) = o0;
    if (st1) *(f32x4*)(hidden + (size_t)lr * D + rb1) = o1;
}

// ---------------- final FC: logits = h3_bf @ fcw_bf^T + fc_b (bf16 MFMA) -----
__global__ __launch_bounds__(256) void k_fc(const __bf16* __restrict__ A,
                                            const __bf16* __restrict__ Bw,
                                            const float* __restrict__ fc_b,
                                            float* __restrict__ Cout) {
    __shared__ __bf16 Bl[3840 * 8];            // 61440 B; tile uses 128*KB=29696
    int tid = threadIdx.x;
    int wg  = blockIdx.x;
    int mt  = wg / NTILES_N, nt = wg - mt * NTILES_N;
    int m0  = mt * 128, n0 = nt * 128;

    // stage B tile (linear 16B-chunk copy; 3840 chunks incl. slack)
    {
        const u32x4* src = (const u32x4*)(Bw + (size_t)n0 * KB);
        u32x4* dst = (u32x4*)Bl;
        u32x4 stg[15];
        #pragma unroll
        for (int it = 0; it < 15; ++it) stg[it] = src[tid + it * 256];
        #pragma unroll
        for (int it = 0; it < 15; ++it) dst[tid + it * 256] = stg[it];
    }
    __syncthreads();

    int lane = tid & 63, wv = tid >> 6;
    int wr = wv >> 1, wc = wv & 1;
    int lr = lane & 15, lq = lane >> 4;
    f32x4 acc[4][4] = {};
    #pragma unroll
    for (int ks = 0; ks < 7; ++ks) {
        bf16x8 af[4], bfr[4];
        #pragma unroll
        for (int i = 0; i < 4; ++i) {
            int arow = m0 + wr * 64 + i * 16 + lr;
            af[i] = *(const bf16x8*)(A + (size_t)arow * KA + (ks * 4 + lq) * 8);
            int brow = wc * 64 + i * 16 + lr;
            bfr[i] = *(const bf16x8*)(Bl + brow * KB + (ks * 4 + lq) * 8);
        }
        #pragma unroll
        for (int i = 0; i < 4; ++i) {
            #pragma unroll
            for (int j = 0; j < 4; ++j) {
                acc[i][j] = __builtin_amdgcn_mfma_f32_16x16x32_bf16(af[i], bfr[j],
                                                                   acc[i][j], 0, 0, 0);
            }
        }
    }
    #pragma unroll
    for (int j = 0; j < 4; ++j) {
        int col = n0 + wc * 64 + j * 16 + lr;
        if (col < VOCAB) {
            float bias = fc_b[col];
            #pragma unroll
            for (int i = 0; i < 4; ++i) {
                #pragma unroll
                for (int r = 0; r < 4; ++r) {
                    int row = m0 + wr * 64 + i * 16 + lq * 4 + r;
                    Cout[(size_t)row * VOCAB + col] = acc[i][j][r] + bias;
                }
            }
        }
    }
}

extern "C" void kernel_launch(void* const* d_in, const int* in_sizes, int n_in,
                              void* d_out, int out_size, void* d_ws, size_t ws_size,
                              hipStream_t stream) {
    const int*   x    = (const int*)  d_in[0];
    const float* emb  = (const float*)d_in[1];
    const float* w_ih = (const float*)d_in[2];
    const float* w_hh = (const float*)d_in[3];
    const float* b_ih = (const float*)d_in[4];
    const float* b_hh = (const float*)d_in[5];
    const float* fc_w = (const float*)d_in[6];
    const float* fc_b = (const float*)d_in[7];
    float* out    = (float*)d_out;
    float* hidden = out + (size_t)M * VOCAB;

    char* ws = (char*)d_ws;
    float*    buf0 = (float*)(ws);                                   // 6,553,600 B
    float*    buf1 = (float*)(ws + 6553600);                         // 6,553,600 B
    float*    wt   = (float*)(ws + 2 * 6553600);                     //   480,000 B
    __bf16*   hbf  = (__bf16*)(ws + 2 * 6553600 + 480000);           // 3,670,016 B
    __bf16*   fwb  = (__bf16*)(ws + 2 * 6553600 + 480000 + 3670016); // 4,695,680 B
    _Float16* whf  = (_Float16*)(ws + 2 * 6553600 + 480000 + 3670016 + 4695680); // 279,552 B

    k_embed <<<(M * D + 255) / 256, 256, 0, stream>>>(x, emb, buf0);
    k_wtrans<<<(NLAYERS * D * D + 255) / 256, 256, 0, stream>>>(w_ih, wt);
    k_whf   <<<(NLAYERS * WRP * WKP + 255) / 256, 256, 0, stream>>>(w_hh, whf);
    k_fcwbf <<<(NPADA * KB + 255) / 256, 256, 0, stream>>>(fc_w, fwb);

    float* cur = buf0;
    float* nxt = buf1;
    for (int l = 0; l < NLAYERS; ++l) {
        k_xw    <<<M / 32, 256, 0, stream>>>(cur, wt + l * D * D,
                                             b_ih + l * D, b_hh + l * D, nxt);
        k_scan_m<<<1, 448, 0, stream>>>(whf + (size_t)l * WRP * WKP, nxt,
                                        hidden + l * NB * D);
        float* tswap = cur; cur = nxt; nxt = tswap;
    }
    k_hbf2<<<(M * KA + 255) / 256, 256, 0, stream>>>(cur, hbf);
    k_fc  <<<64 * NTILES_N, 256, 0, stream>>>(hbf, fwb, fc_b, out);
}

// Round 9
// 1474.076 us; speedup vs baseline: 1.3992x; 1.3992x over previous
//
#include <hip/hip_runtime.h>
#include <hip/hip_bf16.h>

#define VOCAB 10000
#define D 200
#define NLAYERS 3
#define NB 16
#define NS 512
#define M 8192        // NB*NS
#define KA 224        // padded K for A (h3 bf16), 7 * 32
#define KB 232        // padded K for fc_w bf16; 29 16B-chunks (odd -> no LDS bank conflicts)
#define NPADA 10120   // 79*128 = 10112, +8 rows slack for unguarded staging
#define NTILES_N 79
#define WKP 224       // padded K for w_hh f16 fragments (7*32)
#define WRP 208       // padded rows for w_hh (13*16)
#define HSTR 232      // LDS H stride in f16

typedef __bf16 bf16x8 __attribute__((ext_vector_type(8)));
typedef _Float16 f16x8 __attribute__((ext_vector_type(8)));
typedef _Float16 f16x4 __attribute__((ext_vector_type(4)));
typedef float  f32x4  __attribute__((ext_vector_type(4)));
typedef unsigned int u32x4 __attribute__((ext_vector_type(4)));

// ---------------- embedding gather: h0[bs][d] = emb[x[bs]][d] ----------------
__global__ void k_embed(const int* __restrict__ x, const float* __restrict__ emb,
                        float* __restrict__ h0) {
    int i = blockIdx.x * blockDim.x + threadIdx.x;
    if (i < M * D) {
        int bs = i / D;
        int d  = i - bs * D;
        h0[i] = emb[(size_t)x[bs] * D + d];
    }
}

// ---------------- transpose w_ih: wt[l][k][n] = w_ih[l][n][k] ----------------
__global__ void k_wtrans(const float* __restrict__ w_ih, float* __restrict__ wt) {
    int i = blockIdx.x * blockDim.x + threadIdx.x;
    if (i < NLAYERS * D * D) {
        int l = i / (D * D);
        int r = i - l * D * D;
        int k = r / D;
        int n = r - k * D;
        wt[i] = w_ih[l * D * D + n * D + k];
    }
}

// ---------------- w_hh -> f16 padded [NLAYERS][WRP][WKP] ----------------
__global__ void k_whf(const float* __restrict__ w_hh, _Float16* __restrict__ whf) {
    int i = blockIdx.x * blockDim.x + threadIdx.x;
    if (i < NLAYERS * WRP * WKP) {
        int l = i / (WRP * WKP);
        int r = (i / WKP) % WRP;
        int k = i % WKP;
        float v = (r < D && k < D) ? w_hh[l * D * D + r * D + k] : 0.f;
        whf[i] = (_Float16)v;
    }
}

// ---------------- fc_w -> bf16, padded [NPADA][KB] ----------------
__global__ void k_fcwbf(const float* __restrict__ fc_w, __bf16* __restrict__ fwb) {
    int i = blockIdx.x * blockDim.x + threadIdx.x;
    if (i < NPADA * KB) {
        int n = i / KB;
        int k = i - n * KB;
        float v = (n < VOCAB && k < D) ? fc_w[(size_t)n * D + k] : 0.f;
        fwb[i] = (__bf16)v;
    }
}

// ---------------- h3 -> bf16, padded [M][KA] ----------------
__global__ void k_hbf2(const float* __restrict__ h, __bf16* __restrict__ hbf) {
    int i = blockIdx.x * blockDim.x + threadIdx.x;
    if (i < M * KA) {
        int m = i / KA;
        int k = i - m * KA;
        float v = (k < D) ? h[(size_t)m * D + k] : 0.f;
        hbf[i] = (__bf16)v;
    }
}

// ---------------- xw = h @ w_ih^T + b_ih + b_hh  (f32) ----------------
__global__ void k_xw(const float* __restrict__ hin, const float* __restrict__ wt,
                     const float* __restrict__ b_ih, const float* __restrict__ b_hh,
                     float* __restrict__ xw) {
    int m0 = blockIdx.x * 32;
    int n  = threadIdx.x;
    if (n >= D) return;
    float bias = b_ih[n] + b_hh[n];
    for (int g = 0; g < 8; ++g) {
        const float* r0 = hin + (size_t)(m0 + g * 4) * D;
        float a0 = bias, a1 = bias, a2 = bias, a3 = bias;
        for (int k = 0; k < D; k += 4) {
            #pragma unroll
            for (int kk = 0; kk < 4; ++kk) {
                float w = wt[(k + kk) * D + n];      // coalesced, L2-resident
                float h0v = r0[k + kk];              // wave-uniform
                float h1v = r0[D + k + kk];
                float h2v = r0[2 * D + k + kk];
                float h3v = r0[3 * D + k + kk];
                a0 += h0v * w; a1 += h1v * w; a2 += h2v * w; a3 += h3v * w;
            }
        }
        size_t o = (size_t)(m0 + g * 4) * D + n;
        xw[o] = a0; xw[o + D] = a1; xw[o + 2 * D] = a2; xw[o + 3 * D] = a3;
    }
}

__device__ inline float fast_tanh(float x) {
    x = fminf(fmaxf(x, -15.f), 15.f);
    float e = __expf(2.f * x);
    return (e - 1.f) / (e + 1.f);
}

// ---------------- VALU scan (r7-verified, 258us): layers 2,3 ----------------
#define STEP(HR, HW, SIDX)                                                  \
    {                                                                       \
        float xv = xv_next;                                                 \
        int snext = (SIDX) + 1 < NS ? (SIDX) + 1 : NS - 1;                  \
        xv_next = xrow[(size_t)snext * D + rrl];                            \
        f32x4 ac0{0.f,0.f,0.f,0.f}, ac1{0.f,0.f,0.f,0.f};                   \
        _Pragma("unroll")                                                   \
        for (int i = 0; i < 13; ++i) {                                      \
            f32x4 h4 = *(const f32x4*)((HR) + 4 * i);                       \
            ac0 += h4 * w4[0][i];                                           \
            ac1 += h4 * w4[1][i];                                           \
        }                                                                   \
        float s0 = (ac0.x + ac0.y) + (ac0.z + ac0.w);                       \
        float s1 = (ac1.x + ac1.y) + (ac1.z + ac1.w);                       \
        s0 += __shfl_xor(s0, 1);  s0 += __shfl_xor(s0, 2);                  \
        s1 += __shfl_xor(s1, 1);  s1 += __shfl_xor(s1, 2);                  \
        float hn = fast_tanh(xv + ((dg & 1) ? s1 : s0));                    \
        hlast = hn;                                                         \
        if (wlane) {                                                        \
            (HW)[rr] = hn;                                                  \
            xrow[(size_t)(SIDX) * D + rr] = hn;                             \
        }                                                                   \
        __syncthreads();                                                    \
    }

__global__ __attribute__((amdgpu_flat_work_group_size(512, 512),
                          amdgpu_waves_per_eu(2, 2)))
void k_scan(const float* __restrict__ whh,
            float* __restrict__ io,
            float* __restrict__ hidden) {
    __shared__ float hp0[208], hp1[208];
    int t  = threadIdx.x;
    int b  = blockIdx.x;
    int q  = t >> 2;
    int dg = t & 3;
    const bool act = (q < 100);          // quads 0..99 cover rows 0..199
    const int  rr  = 2 * q + (dg & 1);   // row this lane selects / writes
    const int  rrl = act ? rr : 0;       // clamped for loads: no OOB ever
    const bool wlane = act && (dg < 2);  // distinct writer lane per row
    const int  dstart = dg * 52;         // dg==3 covers 156..207 (200.. stay 0)

    f32x4 w4[2][13];
    #pragma unroll
    for (int j = 0; j < 2; ++j)
        #pragma unroll
        for (int i = 0; i < 13; ++i) w4[j][i] = f32x4{0.f, 0.f, 0.f, 0.f};
    if (act) {
        #pragma unroll
        for (int j = 0; j < 2; ++j) {
            const float* wr = whh + (size_t)(2 * q + j) * D + dstart;
            #pragma unroll
            for (int i = 0; i < 11; ++i) w4[j][i] = *(const f32x4*)(wr + 4 * i);
            if (dg < 3) {            // dg==3 has only 44 real weights (156..199)
                w4[j][11] = *(const f32x4*)(wr + 44);
                w4[j][12] = *(const f32x4*)(wr + 48);
            }
        }
    }
    if (t < 208) { hp0[t] = 0.f; hp1[t] = 0.f; }
    __syncthreads();

    float* xrow = io + (size_t)b * NS * D;
    const float* hr0 = hp0 + dstart;
    const float* hr1 = hp1 + dstart;
    float xv_next = xrow[rrl];           // prefetch s=0
    float hlast = 0.f;

    #pragma unroll 1
    for (int s2 = 0; s2 < NS / 2; ++s2) {
        STEP(hr0, hp1, 2 * s2)
        STEP(hr1, hp0, 2 * s2 + 1)
    }
    if (wlane) hidden[b * D + rr] = hlast;
}

// ---------------- MFMA scan (A/B test, layer 1 only) ------------------------
// r8 post-mortem fixes, everything else identical to the PASSED r8 kernel:
// (1) amdgpu_waves_per_eu(2,2): r8's grant was 56 VGPR vs ~120 needed ->
//     operand shuttling, VALUBusy ~49% of the CU. Pin max waves so RA gets 256.
// (2) xw prefetch depth 2 (xw_c/xw_n/xw_p rotation): 14KB/step of xw reads
//     from ONE CU, ~half HBM-missing (FETCH 3.25MB); 1 step (~600cyc) wasn't
//     enough to hide ~900cyc; 2 steps is.
__global__ __attribute__((amdgpu_flat_work_group_size(448, 448),
                          amdgpu_waves_per_eu(2, 2)))
void k_scan_m(const _Float16* __restrict__ whf,   // this layer, [WRP][WKP]
              float* __restrict__ io,             // xw in / h out, [NB][NS][D]
              float* __restrict__ hidden) {       // [NB][D]
    __shared__ _Float16 Hb[2][16][HSTR];
    const int t    = threadIdx.x;
    const int wid  = t >> 6;
    const int lane = t & 63;
    const int lr   = lane & 15;        // A row-in-tile / B batch col / C col
    const int lq   = lane >> 4;        // k-oct selector / C row group
    const int t0   = 2 * wid, t1 = 2 * wid + 1;
    const bool has1 = (t1 < 13);       // wave 6 has only tile 12

    for (int i = t; i < 2 * 16 * HSTR; i += 448) ((_Float16*)Hb)[i] = (_Float16)0.f;

    f16x8 a0[7], a1[7];
    #pragma unroll
    for (int ks = 0; ks < 7; ++ks) {
        a0[ks] = *(const f16x8*)(whf + (size_t)(t0 * 16 + lr) * WKP + ks * 32 + lq * 8);
        if (has1)
            a1[ks] = *(const f16x8*)(whf + (size_t)(t1 * 16 + lr) * WKP + ks * 32 + lq * 8);
    }

    const int rb0 = t0 * 16 + lq * 4;
    const int rb1 = t1 * 16 + lq * 4;
    const bool st0 = (rb0 + 3 < D);
    const bool st1 = has1 && (rb1 + 3 < D);
    const int rb0c = st0 ? rb0 : 0;
    const int rb1c = st1 ? rb1 : 0;

    const float* xb = io + (size_t)lr * NS * D;
    f32x4 xw_c0 = *(const f32x4*)(xb + rb0c);                  // s=0
    f32x4 xw_c1 = *(const f32x4*)(xb + rb1c);
    f32x4 xw_n0 = *(const f32x4*)(xb + (size_t)D + rb0c);      // s=1
    f32x4 xw_n1 = *(const f32x4*)(xb + (size_t)D + rb1c);

    __syncthreads();

    int cur = 0;
    f32x4 o0{0.f,0.f,0.f,0.f}, o1{0.f,0.f,0.f,0.f};
    #pragma unroll 1
    for (int s = 0; s < NS; ++s) {
        const int sp = (s + 2 < NS) ? s + 2 : NS - 1;          // depth-2 prefetch
        f32x4 xw_p0 = *(const f32x4*)(xb + (size_t)sp * D + rb0c);
        f32x4 xw_p1 = *(const f32x4*)(xb + (size_t)sp * D + rb1c);

        f32x4 acc0{0.f,0.f,0.f,0.f}, acc1{0.f,0.f,0.f,0.f};
        #pragma unroll
        for (int ks = 0; ks < 7; ++ks) {
            f16x8 b = *(const f16x8*)(&Hb[cur][lr][ks * 32 + lq * 8]);
            acc0 = __builtin_amdgcn_mfma_f32_16x16x32_f16(a0[ks], b, acc0, 0, 0, 0);
            if (has1)
                acc1 = __builtin_amdgcn_mfma_f32_16x16x32_f16(a1[ks], b, acc1, 0, 0, 0);
        }
        #pragma unroll
        for (int r = 0; r < 4; ++r) {
            o0[r] = fast_tanh(xw_c0[r] + acc0[r]);
            o1[r] = fast_tanh(xw_c1[r] + acc1[r]);
        }
        xw_c0 = xw_n0; xw_c1 = xw_n1;
        xw_n0 = xw_p0; xw_n1 = xw_p1;

        const int nxt = cur ^ 1;
        if (st0) {
            f16x4 hv; hv[0]=(_Float16)o0[0]; hv[1]=(_Float16)o0[1];
                      hv[2]=(_Float16)o0[2]; hv[3]=(_Float16)o0[3];
            *(f16x4*)(&Hb[nxt][lr][rb0]) = hv;
            *(f32x4*)(io + ((size_t)lr * NS + s) * D + rb0) = o0;
        }
        if (st1) {
            f16x4 hv; hv[0]=(_Float16)o1[0]; hv[1]=(_Float16)o1[1];
                      hv[2]=(_Float16)o1[2]; hv[3]=(_Float16)o1[3];
            *(f16x4*)(&Hb[nxt][lr][rb1]) = hv;
            *(f32x4*)(io + ((size_t)lr * NS + s) * D + rb1) = o1;
        }
        __syncthreads();
        cur = nxt;
    }
    if (st0) *(f32x4*)(hidden + (size_t)lr * D + rb0) = o0;
    if (st1) *(f32x4*)(hidden + (size_t)lr * D + rb1) = o1;
}

// ---------------- final FC: logits = h3_bf @ fcw_bf^T + fc_b (bf16 MFMA) -----
__global__ __launch_bounds__(256) void k_fc(const __bf16* __restrict__ A,
                                            const __bf16* __restrict__ Bw,
                                            const float* __restrict__ fc_b,
                                            float* __restrict__ Cout) {
    __shared__ __bf16 Bl[3840 * 8];            // 61440 B; tile uses 128*KB=29696
    int tid = threadIdx.x;
    int wg  = blockIdx.x;
    int mt  = wg / NTILES_N, nt = wg - mt * NTILES_N;
    int m0  = mt * 128, n0 = nt * 128;

    {
        const u32x4* src = (const u32x4*)(Bw + (size_t)n0 * KB);
        u32x4* dst = (u32x4*)Bl;
        u32x4 stg[15];
        #pragma unroll
        for (int it = 0; it < 15; ++it) stg[it] = src[tid + it * 256];
        #pragma unroll
        for (int it = 0; it < 15; ++it) dst[tid + it * 256] = stg[it];
    }
    __syncthreads();

    int lane = tid & 63, wv = tid >> 6;
    int wr = wv >> 1, wc = wv & 1;
    int lr = lane & 15, lq = lane >> 4;
    f32x4 acc[4][4] = {};
    #pragma unroll
    for (int ks = 0; ks < 7; ++ks) {
        bf16x8 af[4], bfr[4];
        #pragma unroll
        for (int i = 0; i < 4; ++i) {
            int arow = m0 + wr * 64 + i * 16 + lr;
            af[i] = *(const bf16x8*)(A + (size_t)arow * KA + (ks * 4 + lq) * 8);
            int brow = wc * 64 + i * 16 + lr;
            bfr[i] = *(const bf16x8*)(Bl + brow * KB + (ks * 4 + lq) * 8);
        }
        #pragma unroll
        for (int i = 0; i < 4; ++i) {
            #pragma unroll
            for (int j = 0; j < 4; ++j) {
                acc[i][j] = __builtin_amdgcn_mfma_f32_16x16x32_bf16(af[i], bfr[j],
                                                                   acc[i][j], 0, 0, 0);
            }
        }
    }
    #pragma unroll
    for (int j = 0; j < 4; ++j) {
        int col = n0 + wc * 64 + j * 16 + lr;
        if (col < VOCAB) {
            float bias = fc_b[col];
            #pragma unroll
            for (int i = 0; i < 4; ++i) {
                #pragma unroll
                for (int r = 0; r < 4; ++r) {
                    int row = m0 + wr * 64 + i * 16 + lq * 4 + r;
                    Cout[(size_t)row * VOCAB + col] = acc[i][j][r] + bias;
                }
            }
        }
    }
}

extern "C" void kernel_launch(void* const* d_in, const int* in_sizes, int n_in,
                              void* d_out, int out_size, void* d_ws, size_t ws_size,
                              hipStream_t stream) {
    const int*   x    = (const int*)  d_in[0];
    const float* emb  = (const float*)d_in[1];
    const float* w_ih = (const float*)d_in[2];
    const float* w_hh = (const float*)d_in[3];
    const float* b_ih = (const float*)d_in[4];
    const float* b_hh = (const float*)d_in[5];
    const float* fc_w = (const float*)d_in[6];
    const float* fc_b = (const float*)d_in[7];
    float* out    = (float*)d_out;
    float* hidden = out + (size_t)M * VOCAB;

    char* ws = (char*)d_ws;
    float*    buf0 = (float*)(ws);                                   // 6,553,600 B
    float*    buf1 = (float*)(ws + 6553600);                         // 6,553,600 B
    float*    wt   = (float*)(ws + 2 * 6553600);                     //   480,000 B
    __bf16*   hbf  = (__bf16*)(ws + 2 * 6553600 + 480000);           // 3,670,016 B
    __bf16*   fwb  = (__bf16*)(ws + 2 * 6553600 + 480000 + 3670016); // 4,695,680 B
    _Float16* whf  = (_Float16*)(ws + 2 * 6553600 + 480000 + 3670016 + 4695680); // 279,552 B

    k_embed <<<(M * D + 255) / 256, 256, 0, stream>>>(x, emb, buf0);
    k_wtrans<<<(NLAYERS * D * D + 255) / 256, 256, 0, stream>>>(w_ih, wt);
    k_whf   <<<(NLAYERS * WRP * WKP + 255) / 256, 256, 0, stream>>>(w_hh, whf);
    k_fcwbf <<<(NPADA * KB + 255) / 256, 256, 0, stream>>>(fc_w, fwb);

    float* cur = buf0;
    float* nxt = buf1;
    for (int l = 0; l < NLAYERS; ++l) {
        k_xw<<<M / 32, 256, 0, stream>>>(cur, wt + l * D * D,
                                         b_ih + l * D, b_hh + l * D, nxt);
        if (l == 0) {   // A/B: MFMA scan (fixed) on layer 1 only
            k_scan_m<<<1, 448, 0, stream>>>(whf + (size_t)l * WRP * WKP, nxt,
                                            hidden + l * NB * D);
        } else {        // proven VALU scan on layers 2,3
            k_scan<<<NB, 512, 0, stream>>>(w_hh + (size_t)l * D * D, nxt,
                                           hidden + l * NB * D);
        }
        float* tswap = cur; cur = nxt; nxt = tswap;
    }
    k_hbf2<<<(M * KA + 255) / 256, 256, 0, stream>>>(cur, hbf);
    k_fc  <<<64 * NTILES_N, 256, 0, stream>>>(hbf, fwb, fc_b, out);
}

// Round 10
// 1433.110 us; speedup vs baseline: 1.4392x; 1.0286x over previous
//
#include <hip/hip_runtime.h>
#include <hip/hip_bf16.h>

#define VOCAB 10000
#define D 200
#define NLAYERS 3
#define NB 16
#define NS 512
#define M 8192        // NB*NS
#define KA 224        // padded K for A (h3 bf16), 7 * 32
#define KB 232        // padded K for fc_w bf16; 29 16B-chunks (odd -> no LDS bank conflicts)
#define NPADA 10120   // 79*128 = 10112, +8 rows slack for unguarded staging
#define NTILES_N 79
#define WKP 224       // padded K for w_hh f16 fragments (7*32)
#define WRP 208       // padded rows for w_hh (13*16)
#define HSTR 232      // LDS H stride in f16

typedef __bf16 bf16x8 __attribute__((ext_vector_type(8)));
typedef _Float16 f16x8 __attribute__((ext_vector_type(8)));
typedef _Float16 f16x4 __attribute__((ext_vector_type(4)));
typedef float  f32x4  __attribute__((ext_vector_type(4)));
typedef unsigned int u32x4 __attribute__((ext_vector_type(4)));

// ---------------- embedding gather: h0[bs][d] = emb[x[bs]][d] ----------------
__global__ void k_embed(const int* __restrict__ x, const float* __restrict__ emb,
                        float* __restrict__ h0) {
    int i = blockIdx.x * blockDim.x + threadIdx.x;
    if (i < M * D) {
        int bs = i / D;
        int d  = i - bs * D;
        h0[i] = emb[(size_t)x[bs] * D + d];
    }
}

// ---------------- transpose w_ih: wt[l][k][n] = w_ih[l][n][k] ----------------
__global__ void k_wtrans(const float* __restrict__ w_ih, float* __restrict__ wt) {
    int i = blockIdx.x * blockDim.x + threadIdx.x;
    if (i < NLAYERS * D * D) {
        int l = i / (D * D);
        int r = i - l * D * D;
        int k = r / D;
        int n = r - k * D;
        wt[i] = w_ih[l * D * D + n * D + k];
    }
}

// ---------------- w_hh -> f16 padded [NLAYERS][WRP][WKP] ----------------
__global__ void k_whf(const float* __restrict__ w_hh, _Float16* __restrict__ whf) {
    int i = blockIdx.x * blockDim.x + threadIdx.x;
    if (i < NLAYERS * WRP * WKP) {
        int l = i / (WRP * WKP);
        int r = (i / WKP) % WRP;
        int k = i % WKP;
        float v = (r < D && k < D) ? w_hh[l * D * D + r * D + k] : 0.f;
        whf[i] = (_Float16)v;
    }
}

// ---------------- fc_w -> bf16, padded [NPADA][KB] ----------------
__global__ void k_fcwbf(const float* __restrict__ fc_w, __bf16* __restrict__ fwb) {
    int i = blockIdx.x * blockDim.x + threadIdx.x;
    if (i < NPADA * KB) {
        int n = i / KB;
        int k = i - n * KB;
        float v = (n < VOCAB && k < D) ? fc_w[(size_t)n * D + k] : 0.f;
        fwb[i] = (__bf16)v;
    }
}

// ---------------- h3 -> bf16, padded [M][KA] ----------------
__global__ void k_hbf2(const float* __restrict__ h, __bf16* __restrict__ hbf) {
    int i = blockIdx.x * blockDim.x + threadIdx.x;
    if (i < M * KA) {
        int m = i / KA;
        int k = i - m * KA;
        float v = (k < D) ? h[(size_t)m * D + k] : 0.f;
        hbf[i] = (__bf16)v;
    }
}

// ---------------- xw = h @ w_ih^T + b_ih + b_hh  (f32) ----------------
__global__ void k_xw(const float* __restrict__ hin, const float* __restrict__ wt,
                     const float* __restrict__ b_ih, const float* __restrict__ b_hh,
                     float* __restrict__ xw) {
    int m0 = blockIdx.x * 32;
    int n  = threadIdx.x;
    if (n >= D) return;
    float bias = b_ih[n] + b_hh[n];
    for (int g = 0; g < 8; ++g) {
        const float* r0 = hin + (size_t)(m0 + g * 4) * D;
        float a0 = bias, a1 = bias, a2 = bias, a3 = bias;
        for (int k = 0; k < D; k += 4) {
            #pragma unroll
            for (int kk = 0; kk < 4; ++kk) {
                float w = wt[(k + kk) * D + n];      // coalesced, L2-resident
                float h0v = r0[k + kk];              // wave-uniform
                float h1v = r0[D + k + kk];
                float h2v = r0[2 * D + k + kk];
                float h3v = r0[3 * D + k + kk];
                a0 += h0v * w; a1 += h1v * w; a2 += h2v * w; a3 += h3v * w;
            }
        }
        size_t o = (size_t)(m0 + g * 4) * D + n;
        xw[o] = a0; xw[o + D] = a1; xw[o + 2 * D] = a2; xw[o + 3 * D] = a3;
    }
}

__device__ inline float fast_tanh(float x) {
    x = fminf(fmaxf(x, -15.f), 15.f);
    float e = __expf(2.f * x);
    return (e - 1.f) / (e + 1.f);
}

// ---------------- VALU scan (r7-verified, 258us): layers 2,3 ----------------
#define STEP(HR, HW, SIDX)                                                  \
    {                                                                       \
        float xv = xv_next;                                                 \
        int snext = (SIDX) + 1 < NS ? (SIDX) + 1 : NS - 1;                  \
        xv_next = xrow[(size_t)snext * D + rrl];                            \
        f32x4 ac0{0.f,0.f,0.f,0.f}, ac1{0.f,0.f,0.f,0.f};                   \
        _Pragma("unroll")                                                   \
        for (int i = 0; i < 13; ++i) {                                      \
            f32x4 h4 = *(const f32x4*)((HR) + 4 * i);                       \
            ac0 += h4 * w4[0][i];                                           \
            ac1 += h4 * w4[1][i];                                           \
        }                                                                   \
        float s0 = (ac0.x + ac0.y) + (ac0.z + ac0.w);                       \
        float s1 = (ac1.x + ac1.y) + (ac1.z + ac1.w);                       \
        s0 += __shfl_xor(s0, 1);  s0 += __shfl_xor(s0, 2);                  \
        s1 += __shfl_xor(s1, 1);  s1 += __shfl_xor(s1, 2);                  \
        float hn = fast_tanh(xv + ((dg & 1) ? s1 : s0));                    \
        hlast = hn;                                                         \
        if (wlane) {                                                        \
            (HW)[rr] = hn;                                                  \
            xrow[(size_t)(SIDX) * D + rr] = hn;                             \
        }                                                                   \
        __syncthreads();                                                    \
    }

__global__ __attribute__((amdgpu_flat_work_group_size(512, 512),
                          amdgpu_waves_per_eu(2, 2)))
void k_scan(const float* __restrict__ whh,
            float* __restrict__ io,
            float* __restrict__ hidden) {
    __shared__ float hp0[208], hp1[208];
    int t  = threadIdx.x;
    int b  = blockIdx.x;
    int q  = t >> 2;
    int dg = t & 3;
    const bool act = (q < 100);          // quads 0..99 cover rows 0..199
    const int  rr  = 2 * q + (dg & 1);   // row this lane selects / writes
    const int  rrl = act ? rr : 0;       // clamped for loads: no OOB ever
    const bool wlane = act && (dg < 2);  // distinct writer lane per row
    const int  dstart = dg * 52;         // dg==3 covers 156..207 (200.. stay 0)

    f32x4 w4[2][13];
    #pragma unroll
    for (int j = 0; j < 2; ++j)
        #pragma unroll
        for (int i = 0; i < 13; ++i) w4[j][i] = f32x4{0.f, 0.f, 0.f, 0.f};
    if (act) {
        #pragma unroll
        for (int j = 0; j < 2; ++j) {
            const float* wr = whh + (size_t)(2 * q + j) * D + dstart;
            #pragma unroll
            for (int i = 0; i < 11; ++i) w4[j][i] = *(const f32x4*)(wr + 4 * i);
            if (dg < 3) {            // dg==3 has only 44 real weights (156..199)
                w4[j][11] = *(const f32x4*)(wr + 44);
                w4[j][12] = *(const f32x4*)(wr + 48);
            }
        }
    }
    if (t < 208) { hp0[t] = 0.f; hp1[t] = 0.f; }
    __syncthreads();

    float* xrow = io + (size_t)b * NS * D;
    const float* hr0 = hp0 + dstart;
    const float* hr1 = hp1 + dstart;
    float xv_next = xrow[rrl];           // prefetch s=0
    float hlast = 0.f;

    #pragma unroll 1
    for (int s2 = 0; s2 < NS / 2; ++s2) {
        STEP(hr0, hp1, 2 * s2)
        STEP(hr1, hp0, 2 * s2 + 1)
    }
    if (wlane) hidden[b * D + rr] = hlast;
}

// ---------------- MFMA scan (A/B test, layer 1 only) ------------------------
// r10 change vs the r9-passed kernel, ONE structural lever: replace
// __syncthreads() (which compiles to s_waitcnt vmcnt(0) lgkmcnt(0); s_barrier
// and force-drains the xw prefetch + h stores EVERY step -> ~900cyc HBM
// latency exposed per step) with lgkmcnt(0)-only + raw s_barrier. ds_reads
// are consumed by MFMAs before the barrier; ds_writes drained by the explicit
// lgkmcnt(0); double-buffer gives one-barrier WAR separation; global loads/
// stores may now span steps. Plus: even/odd-ks accumulator split (serial
// MFMA chain 7 -> 4). Numerics: f32 adds reordered only.
__global__ __attribute__((amdgpu_flat_work_group_size(448, 448),
                          amdgpu_waves_per_eu(2, 2)))
void k_scan_m(const _Float16* __restrict__ whf,   // this layer, [WRP][WKP]
              float* __restrict__ io,             // xw in / h out, [NB][NS][D]
              float* __restrict__ hidden) {       // [NB][D]
    __shared__ _Float16 Hb[2][16][HSTR];
    const int t    = threadIdx.x;
    const int wid  = t >> 6;
    const int lane = t & 63;
    const int lr   = lane & 15;        // A row-in-tile / B batch col / C col
    const int lq   = lane >> 4;        // k-oct selector / C row group
    const int t0   = 2 * wid, t1 = 2 * wid + 1;
    const bool has1 = (t1 < 13);       // wave 6 has only tile 12

    for (int i = t; i < 2 * 16 * HSTR; i += 448) ((_Float16*)Hb)[i] = (_Float16)0.f;

    f16x8 a0[7], a1[7];
    #pragma unroll
    for (int ks = 0; ks < 7; ++ks) {
        a0[ks] = *(const f16x8*)(whf + (size_t)(t0 * 16 + lr) * WKP + ks * 32 + lq * 8);
        if (has1)
            a1[ks] = *(const f16x8*)(whf + (size_t)(t1 * 16 + lr) * WKP + ks * 32 + lq * 8);
    }

    const int rb0 = t0 * 16 + lq * 4;
    const int rb1 = t1 * 16 + lq * 4;
    const bool st0 = (rb0 + 3 < D);
    const bool st1 = has1 && (rb1 + 3 < D);
    const int rb0c = st0 ? rb0 : 0;
    const int rb1c = st1 ? rb1 : 0;

    const float* xb = io + (size_t)lr * NS * D;
    f32x4 xw_c0 = *(const f32x4*)(xb + rb0c);                  // s=0
    f32x4 xw_c1 = *(const f32x4*)(xb + rb1c);
    f32x4 xw_n0 = *(const f32x4*)(xb + (size_t)D + rb0c);      // s=1
    f32x4 xw_n1 = *(const f32x4*)(xb + (size_t)D + rb1c);

    __syncthreads();

    int cur = 0;
    f32x4 o0{0.f,0.f,0.f,0.f}, o1{0.f,0.f,0.f,0.f};
    #pragma unroll 1
    for (int s = 0; s < NS; ++s) {
        const int sp = (s + 2 < NS) ? s + 2 : NS - 1;          // depth-2 prefetch
        f32x4 xw_p0 = *(const f32x4*)(xb + (size_t)sp * D + rb0c);
        f32x4 xw_p1 = *(const f32x4*)(xb + (size_t)sp * D + rb1c);

        // even/odd-ks split: two independent MFMA chains per tile
        f32x4 acc0a{0.f,0.f,0.f,0.f}, acc0b{0.f,0.f,0.f,0.f};
        f32x4 acc1a{0.f,0.f,0.f,0.f}, acc1b{0.f,0.f,0.f,0.f};
        #pragma unroll
        for (int ks = 0; ks < 7; ks += 2) {
            f16x8 b = *(const f16x8*)(&Hb[cur][lr][ks * 32 + lq * 8]);
            acc0a = __builtin_amdgcn_mfma_f32_16x16x32_f16(a0[ks], b, acc0a, 0, 0, 0);
            if (has1)
                acc1a = __builtin_amdgcn_mfma_f32_16x16x32_f16(a1[ks], b, acc1a, 0, 0, 0);
        }
        #pragma unroll
        for (int ks = 1; ks < 7; ks += 2) {
            f16x8 b = *(const f16x8*)(&Hb[cur][lr][ks * 32 + lq * 8]);
            acc0b = __builtin_amdgcn_mfma_f32_16x16x32_f16(a0[ks], b, acc0b, 0, 0, 0);
            if (has1)
                acc1b = __builtin_amdgcn_mfma_f32_16x16x32_f16(a1[ks], b, acc1b, 0, 0, 0);
        }
        f32x4 acc0 = acc0a + acc0b;
        f32x4 acc1 = acc1a + acc1b;
        #pragma unroll
        for (int r = 0; r < 4; ++r) {
            o0[r] = fast_tanh(xw_c0[r] + acc0[r]);
            o1[r] = fast_tanh(xw_c1[r] + acc1[r]);
        }
        xw_c0 = xw_n0; xw_c1 = xw_n1;
        xw_n0 = xw_p0; xw_n1 = xw_p1;

        const int nxt = cur ^ 1;
        if (st0) {
            f16x4 hv; hv[0]=(_Float16)o0[0]; hv[1]=(_Float16)o0[1];
                      hv[2]=(_Float16)o0[2]; hv[3]=(_Float16)o0[3];
            *(f16x4*)(&Hb[nxt][lr][rb0]) = hv;
            *(f32x4*)(io + ((size_t)lr * NS + s) * D + rb0) = o0;
        }
        if (st1) {
            f16x4 hv; hv[0]=(_Float16)o1[0]; hv[1]=(_Float16)o1[1];
                      hv[2]=(_Float16)o1[2]; hv[3]=(_Float16)o1[3];
            *(f16x4*)(&Hb[nxt][lr][rb1]) = hv;
            *(f32x4*)(io + ((size_t)lr * NS + s) * D + rb1) = o1;
        }
        // barrier WITHOUT vmcnt drain: LDS-visibility only.
        asm volatile("s_waitcnt lgkmcnt(0)" ::: "memory");
        __builtin_amdgcn_s_barrier();
        asm volatile("" ::: "memory");
        cur = nxt;
    }
    if (st0) *(f32x4*)(hidden + (size_t)lr * D + rb0) = o0;
    if (st1) *(f32x4*)(hidden + (size_t)lr * D + rb1) = o1;
}

// ---------------- final FC: logits = h3_bf @ fcw_bf^T + fc_b (bf16 MFMA) -----
__global__ __launch_bounds__(256) void k_fc(const __bf16* __restrict__ A,
                                            const __bf16* __restrict__ Bw,
                                            const float* __restrict__ fc_b,
                                            float* __restrict__ Cout) {
    __shared__ __bf16 Bl[3840 * 8];            // 61440 B; tile uses 128*KB=29696
    int tid = threadIdx.x;
    int wg  = blockIdx.x;
    int mt  = wg / NTILES_N, nt = wg - mt * NTILES_N;
    int m0  = mt * 128, n0 = nt * 128;

    {
        const u32x4* src = (const u32x4*)(Bw + (size_t)n0 * KB);
        u32x4* dst = (u32x4*)Bl;
        u32x4 stg[15];
        #pragma unroll
        for (int it = 0; it < 15; ++it) stg[it] = src[tid + it * 256];
        #pragma unroll
        for (int it = 0; it < 15; ++it) dst[tid + it * 256] = stg[it];
    }
    __syncthreads();

    int lane = tid & 63, wv = tid >> 6;
    int wr = wv >> 1, wc = wv & 1;
    int lr = lane & 15, lq = lane >> 4;
    f32x4 acc[4][4] = {};
    #pragma unroll
    for (int ks = 0; ks < 7; ++ks) {
        bf16x8 af[4], bfr[4];
        #pragma unroll
        for (int i = 0; i < 4; ++i) {
            int arow = m0 + wr * 64 + i * 16 + lr;
            af[i] = *(const bf16x8*)(A + (size_t)arow * KA + (ks * 4 + lq) * 8);
            int brow = wc * 64 + i * 16 + lr;
            bfr[i] = *(const bf16x8*)(Bl + brow * KB + (ks * 4 + lq) * 8);
        }
        #pragma unroll
        for (int i = 0; i < 4; ++i) {
            #pragma unroll
            for (int j = 0; j < 4; ++j) {
                acc[i][j] = __builtin_amdgcn_mfma_f32_16x16x32_bf16(af[i], bfr[j],
                                                                   acc[i][j], 0, 0, 0);
            }
        }
    }
    #pragma unroll
    for (int j = 0; j < 4; ++j) {
        int col = n0 + wc * 64 + j * 16 + lr;
        if (col < VOCAB) {
            float bias = fc_b[col];
            #pragma unroll
            for (int i = 0; i < 4; ++i) {
                #pragma unroll
                for (int r = 0; r < 4; ++r) {
                    int row = m0 + wr * 64 + i * 16 + lq * 4 + r;
                    Cout[(size_t)row * VOCAB + col] = acc[i][j][r] + bias;
                }
            }
        }
    }
}

extern "C" void kernel_launch(void* const* d_in, const int* in_sizes, int n_in,
                              void* d_out, int out_size, void* d_ws, size_t ws_size,
                              hipStream_t stream) {
    const int*   x    = (const int*)  d_in[0];
    const float* emb  = (const float*)d_in[1];
    const float* w_ih = (const float*)d_in[2];
    const float* w_hh = (const float*)d_in[3];
    const float* b_ih = (const float*)d_in[4];
    const float* b_hh = (const float*)d_in[5];
    const float* fc_w = (const float*)d_in[6];
    const float* fc_b = (const float*)d_in[7];
    float* out    = (float*)d_out;
    float* hidden = out + (size_t)M * VOCAB;

    char* ws = (char*)d_ws;
    float*    buf0 = (float*)(ws);                                   // 6,553,600 B
    float*    buf1 = (float*)(ws + 6553600);                         // 6,553,600 B
    float*    wt   = (float*)(ws + 2 * 6553600);                     //   480,000 B
    __bf16*   hbf  = (__bf16*)(ws + 2 * 6553600 + 480000);           // 3,670,016 B
    __bf16*   fwb  = (__bf16*)(ws + 2 * 6553600 + 480000 + 3670016); // 4,695,680 B
    _Float16* whf  = (_Float16*)(ws + 2 * 6553600 + 480000 + 3670016 + 4695680); // 279,552 B

    k_embed <<<(M * D + 255) / 256, 256, 0, stream>>>(x, emb, buf0);
    k_wtrans<<<(NLAYERS * D * D + 255) / 256, 256, 0, stream>>>(w_ih, wt);
    k_whf   <<<(NLAYERS * WRP * WKP + 255) / 256, 256, 0, stream>>>(w_hh, whf);
    k_fcwbf <<<(NPADA * KB + 255) / 256, 256, 0, stream>>>(fc_w, fwb);

    float* cur = buf0;
    float* nxt = buf1;
    for (int l = 0; l < NLAYERS; ++l) {
        k_xw<<<M / 32, 256, 0, stream>>>(cur, wt + l * D * D,
                                         b_ih + l * D, b_hh + l * D, nxt);
        if (l == 0) {   // A/B: MFMA scan (non-draining barrier) on layer 1
            k_scan_m<<<1, 448, 0, stream>>>(whf + (size_t)l * WRP * WKP, nxt,
                                            hidden + l * NB * D);
        } else {        // proven VALU scan on layers 2,3
            k_scan<<<NB, 512, 0, stream>>>(w_hh + (size_t)l * D * D, nxt,
                                           hidden + l * NB * D);
        }
        float* tswap = cur; cur = nxt; nxt = tswap;
    }
    k_hbf2<<<(M * KA + 255) / 256, 256, 0, stream>>>(cur, hbf);
    k_fc  <<<64 * NTILES_N, 256, 0, stream>>>(hbf, fwb, fc_b, out);
}

// Round 11
// 866.721 us; speedup vs baseline: 2.3796x; 1.6535x over previous
//
#include <hip/hip_runtime.h>
#include <hip/hip_bf16.h>

#define VOCAB 10000
#define D 200
#define NLAYERS 3
#define NB 16
#define NS 512
#define M 8192        // NB*NS
#define KA 224        // padded K for A (h3 bf16), 7 * 32
#define KB 232        // padded K for fc_w bf16; 29 16B-chunks (odd -> no LDS bank conflicts)
#define NPADA 10120   // 79*128 = 10112, +8 rows slack for unguarded staging
#define NTILES_N 79

// ws layout (bytes)
#define OFF_BUF0 0u                 // 6,553,600  embed h0, then stage0 cells
#define OFF_BUF1 6553600u           // 6,553,600  xw0 (layer-0 input proj)
#define OFF_WT   13107200u          //   480,000  w_ih transposed (all layers)
#define OFF_HBF  13587200u          // 3,670,016  h3 bf16 [M][KA]
#define OFF_FWB  17257216u          // 4,695,680  fc_w bf16 [NPADA][KB]
#define OFF_STG1 21952896u          // 6,553,600  stage1 cells
#define WS_NEED  28506496u

typedef __bf16 bf16x8 __attribute__((ext_vector_type(8)));
typedef float  f32x4  __attribute__((ext_vector_type(4)));
typedef unsigned int u32x4 __attribute__((ext_vector_type(4)));

// ---------------- embedding gather ----------------
__global__ void k_embed(const int* __restrict__ x, const float* __restrict__ emb,
                        float* __restrict__ h0) {
    int i = blockIdx.x * blockDim.x + threadIdx.x;
    if (i < M * D) {
        int bs = i / D;
        int d  = i - bs * D;
        h0[i] = emb[(size_t)x[bs] * D + d];
    }
}

// ---------------- transpose w_ih ----------------
__global__ void k_wtrans(const float* __restrict__ w_ih, float* __restrict__ wt) {
    int i = blockIdx.x * blockDim.x + threadIdx.x;
    if (i < NLAYERS * D * D) {
        int l = i / (D * D);
        int r = i - l * D * D;
        int k = r / D;
        int n = r - k * D;
        wt[i] = w_ih[l * D * D + n * D + k];
    }
}

// ---------------- fc_w -> bf16 padded ----------------
__global__ void k_fcwbf(const float* __restrict__ fc_w, __bf16* __restrict__ fwb) {
    int i = blockIdx.x * blockDim.x + threadIdx.x;
    if (i < NPADA * KB) {
        int n = i / KB;
        int k = i - n * KB;
        float v = (n < VOCAB && k < D) ? fc_w[(size_t)n * D + k] : 0.f;
        fwb[i] = (__bf16)v;
    }
}

// ---------------- h3 -> bf16 padded (fallback path only) ----------------
__global__ void k_hbf2(const float* __restrict__ h, __bf16* __restrict__ hbf) {
    int i = blockIdx.x * blockDim.x + threadIdx.x;
    if (i < M * KA) {
        int m = i / KA;
        int k = i - m * KA;
        float v = (k < D) ? h[(size_t)m * D + k] : 0.f;
        hbf[i] = (__bf16)v;
    }
}

// ---------------- zero helper (stage cells / hbf pads each launch) ----------
__global__ void k_zero(u32x4* __restrict__ p, int n4) {
    int i = blockIdx.x * blockDim.x + threadIdx.x;
    if (i < n4) p[i] = u32x4{0u, 0u, 0u, 0u};
}

// ---------------- xw = h @ w_ih^T + b_ih + b_hh  (f32) ----------------
__global__ void k_xw(const float* __restrict__ hin, const float* __restrict__ wt,
                     const float* __restrict__ b_ih, const float* __restrict__ b_hh,
                     float* __restrict__ xw) {
    int m0 = blockIdx.x * 32;
    int n  = threadIdx.x;
    if (n >= D) return;
    float bias = b_ih[n] + b_hh[n];
    for (int g = 0; g < 8; ++g) {
        const float* r0 = hin + (size_t)(m0 + g * 4) * D;
        float a0 = bias, a1 = bias, a2 = bias, a3 = bias;
        for (int k = 0; k < D; k += 4) {
            #pragma unroll
            for (int kk = 0; kk < 4; ++kk) {
                float w = wt[(k + kk) * D + n];
                float h0v = r0[k + kk];
                float h1v = r0[D + k + kk];
                float h2v = r0[2 * D + k + kk];
                float h3v = r0[3 * D + k + kk];
                a0 += h0v * w; a1 += h1v * w; a2 += h2v * w; a3 += h3v * w;
            }
        }
        size_t o = (size_t)(m0 + g * 4) * D + n;
        xw[o] = a0; xw[o + D] = a1; xw[o + 2 * D] = a2; xw[o + 3 * D] = a3;
    }
}

__device__ inline float fast_tanh(float x) {
    x = fminf(fmaxf(x, -15.f), 15.f);
    float e = __expf(2.f * x);
    return (e - 1.f) / (e + 1.f);
}

// ---------------- pipelined 3-layer scan, 48 WGs (16 batch x 3 layers) ------
// Wavefront pipeline: h_l[s] needs h_{l-1}[s] and h_l[s-1] only. WG (b,l)
// runs the r5-verified VALU step; l>0 folds the input projection in-kernel
// (second 104-VGPR w_ih slice; r7 proved AGPR-demotion overflow is cheap).
// Handoff: one u32 cell per (l,b,s,row), value = ~bits(h). Cell==0 means
// unwritten (bits(h)==0xFFFFFFFF would be NaN — tanh can't produce it), so
// each cell self-announces: no fences, no cross-address ordering, no
// deadlock sentinel collision. Agent-scope atomics are L3-coherent across
// XCDs. waves_per_eu(2,2) => 8 waves/CU max => one WG per CU => all 48
// co-resident (<<256 CUs), spin-wait is safe.
__global__ __attribute__((amdgpu_flat_work_group_size(512, 512),
                          amdgpu_waves_per_eu(2, 2)))
void k_scan_pipe(const float* __restrict__ whh_all,
                 const float* __restrict__ wih_all,
                 const float* __restrict__ b_ih,
                 const float* __restrict__ b_hh,
                 const float* __restrict__ xw0,
                 unsigned* __restrict__ stage0,
                 unsigned* __restrict__ stage1,
                 __bf16* __restrict__ hbf,
                 float* __restrict__ hidden) {
    __shared__ float hp0[208], hp1[208], hin[208];
    const int bid = blockIdx.x;
    const int l   = bid >> 4;            // 16 blocks per layer; layer 0 first
    const int b   = bid & 15;
    const int t   = threadIdx.x;
    const int q   = t >> 2, dg = t & 3;
    const bool act = (q < 100);
    const int  rr  = 2 * q + (dg & 1);
    const int  rrl = act ? rr : 0;
    const bool wlane = act && (dg < 2);
    const int  dstart = dg * 52;

    f32x4 wh[2][13], wi[2][13];
    #pragma unroll
    for (int j = 0; j < 2; ++j)
        #pragma unroll
        for (int i = 0; i < 13; ++i) {
            wh[j][i] = f32x4{0.f, 0.f, 0.f, 0.f};
            wi[j][i] = f32x4{0.f, 0.f, 0.f, 0.f};
        }
    if (act) {
        #pragma unroll
        for (int j = 0; j < 2; ++j) {
            const float* wr = whh_all + (size_t)l * D * D + (size_t)(2 * q + j) * D + dstart;
            #pragma unroll
            for (int i = 0; i < 11; ++i) wh[j][i] = *(const f32x4*)(wr + 4 * i);
            if (dg < 3) {
                wh[j][11] = *(const f32x4*)(wr + 44);
                wh[j][12] = *(const f32x4*)(wr + 48);
            }
        }
        if (l > 0) {
            #pragma unroll
            for (int j = 0; j < 2; ++j) {
                const float* wr = wih_all + (size_t)l * D * D + (size_t)(2 * q + j) * D + dstart;
                #pragma unroll
                for (int i = 0; i < 11; ++i) wi[j][i] = *(const f32x4*)(wr + 4 * i);
                if (dg < 3) {
                    wi[j][11] = *(const f32x4*)(wr + 44);
                    wi[j][12] = *(const f32x4*)(wr + 48);
                }
            }
        }
    }
    float bias = 0.f;
    if (l > 0 && act) bias = b_ih[l * D + rr] + b_hh[l * D + rr];

    if (t < 208) { hp0[t] = 0.f; hp1[t] = 0.f; hin[t] = 0.f; }
    __syncthreads();

    const float* xrow = xw0 + (size_t)b * NS * D;                 // l==0 only
    const unsigned* sin = (l == 1) ? stage0 + (size_t)b * NS * 200
                        : (l == 2) ? stage1 + (size_t)b * NS * 200 : nullptr;
    unsigned* sout = (l == 0) ? stage0 + (size_t)b * NS * 200
                   : (l == 1) ? stage1 + (size_t)b * NS * 200 : nullptr;

    float xv_next = (l == 0) ? xrow[rrl] : 0.f;
    float hlast = 0.f;
    const float* hi = hin + dstart;

    #pragma unroll 1
    for (int s = 0; s < NS; ++s) {
        float xv;
        if (l == 0) {
            xv = xv_next;
            const int sn = (s + 1 < NS) ? s + 1 : NS - 1;
            xv_next = xrow[(size_t)sn * D + rrl];
        } else {
            if (t < 200) {   // spin on self-announcing cell, stage into LDS
                const unsigned* p = sin + (size_t)s * 200 + t;
                unsigned v;
                do {
                    v = __hip_atomic_load(p, __ATOMIC_RELAXED,
                                          __HIP_MEMORY_SCOPE_AGENT);
                } while (v == 0u);
                hin[t] = __builtin_bit_cast(float, ~v);
            }
            asm volatile("s_waitcnt lgkmcnt(0)" ::: "memory");
            __builtin_amdgcn_s_barrier();
            asm volatile("" ::: "memory");
            xv = bias;
        }
        const float* hr = ((s & 1) ? hp1 : hp0) + dstart;
        float* hw = (s & 1) ? hp0 : hp1;
        f32x4 ac0{0.f,0.f,0.f,0.f}, ac1{0.f,0.f,0.f,0.f};
        #pragma unroll
        for (int i = 0; i < 13; ++i) {
            f32x4 h4 = *(const f32x4*)(hr + 4 * i);
            ac0 += h4 * wh[0][i];
            ac1 += h4 * wh[1][i];
        }
        if (l > 0) {
            #pragma unroll
            for (int i = 0; i < 13; ++i) {
                f32x4 g4 = *(const f32x4*)(hi + 4 * i);
                ac0 += g4 * wi[0][i];
                ac1 += g4 * wi[1][i];
            }
        }
        float s0 = (ac0.x + ac0.y) + (ac0.z + ac0.w);
        float s1 = (ac1.x + ac1.y) + (ac1.z + ac1.w);
        s0 += __shfl_xor(s0, 1);  s0 += __shfl_xor(s0, 2);
        s1 += __shfl_xor(s1, 1);  s1 += __shfl_xor(s1, 2);
        float hn = fast_tanh(xv + ((dg & 1) ? s1 : s0));
        hlast = hn;
        if (wlane) {
            hw[rr] = hn;
            if (l < 2) {
                __hip_atomic_store(sout + (size_t)s * 200 + rr,
                                   ~__builtin_bit_cast(unsigned, hn),
                                   __ATOMIC_RELAXED, __HIP_MEMORY_SCOPE_AGENT);
            } else {
                hbf[((size_t)b * NS + s) * KA + rr] = (__bf16)hn;
            }
        }
        asm volatile("s_waitcnt lgkmcnt(0)" ::: "memory");
        __builtin_amdgcn_s_barrier();
        asm volatile("" ::: "memory");
    }
    if (wlane) hidden[(size_t)l * NB * D + b * D + rr] = hlast;
}

// ---------------- VALU scan (r7-verified, fallback path) ----------------
#define STEP(HR, HW, SIDX)                                                  \
    {                                                                       \
        float xv = xv_next;                                                 \
        int snext = (SIDX) + 1 < NS ? (SIDX) + 1 : NS - 1;                  \
        xv_next = xrow[(size_t)snext * D + rrl];                            \
        f32x4 ac0{0.f,0.f,0.f,0.f}, ac1{0.f,0.f,0.f,0.f};                   \
        _Pragma("unroll")                                                   \
        for (int i = 0; i < 13; ++i) {                                      \
            f32x4 h4 = *(const f32x4*)((HR) + 4 * i);                       \
            ac0 += h4 * w4[0][i];                                           \
            ac1 += h4 * w4[1][i];                                           \
        }                                                                   \
        float s0 = (ac0.x + ac0.y) + (ac0.z + ac0.w);                       \
        float s1 = (ac1.x + ac1.y) + (ac1.z + ac1.w);                       \
        s0 += __shfl_xor(s0, 1);  s0 += __shfl_xor(s0, 2);                  \
        s1 += __shfl_xor(s1, 1);  s1 += __shfl_xor(s1, 2);                  \
        float hn = fast_tanh(xv + ((dg & 1) ? s1 : s0));                    \
        hlast = hn;                                                         \
        if (wlane) {                                                        \
            (HW)[rr] = hn;                                                  \
            xrow[(size_t)(SIDX) * D + rr] = hn;                             \
        }                                                                   \
        __syncthreads();                                                    \
    }

__global__ __attribute__((amdgpu_flat_work_group_size(512, 512),
                          amdgpu_waves_per_eu(2, 2)))
void k_scan(const float* __restrict__ whh,
            float* __restrict__ io,
            float* __restrict__ hidden) {
    __shared__ float hp0[208], hp1[208];
    int t  = threadIdx.x;
    int b  = blockIdx.x;
    int q  = t >> 2;
    int dg = t & 3;
    const bool act = (q < 100);
    const int  rr  = 2 * q + (dg & 1);
    const int  rrl = act ? rr : 0;
    const bool wlane = act && (dg < 2);
    const int  dstart = dg * 52;

    f32x4 w4[2][13];
    #pragma unroll
    for (int j = 0; j < 2; ++j)
        #pragma unroll
        for (int i = 0; i < 13; ++i) w4[j][i] = f32x4{0.f, 0.f, 0.f, 0.f};
    if (act) {
        #pragma unroll
        for (int j = 0; j < 2; ++j) {
            const float* wr = whh + (size_t)(2 * q + j) * D + dstart;
            #pragma unroll
            for (int i = 0; i < 11; ++i) w4[j][i] = *(const f32x4*)(wr + 4 * i);
            if (dg < 3) {
                w4[j][11] = *(const f32x4*)(wr + 44);
                w4[j][12] = *(const f32x4*)(wr + 48);
            }
        }
    }
    if (t < 208) { hp0[t] = 0.f; hp1[t] = 0.f; }
    __syncthreads();

    float* xrow = io + (size_t)b * NS * D;
    const float* hr0 = hp0 + dstart;
    const float* hr1 = hp1 + dstart;
    float xv_next = xrow[rrl];
    float hlast = 0.f;

    #pragma unroll 1
    for (int s2 = 0; s2 < NS / 2; ++s2) {
        STEP(hr0, hp1, 2 * s2)
        STEP(hr1, hp0, 2 * s2 + 1)
    }
    if (wlane) hidden[b * D + rr] = hlast;
}

// ---------------- final FC: logits = h3_bf @ fcw_bf^T + fc_b (bf16 MFMA) -----
__global__ __launch_bounds__(256) void k_fc(const __bf16* __restrict__ A,
                                            const __bf16* __restrict__ Bw,
                                            const float* __restrict__ fc_b,
                                            float* __restrict__ Cout) {
    __shared__ __bf16 Bl[3840 * 8];
    int tid = threadIdx.x;
    int wg  = blockIdx.x;
    int mt  = wg / NTILES_N, nt = wg - mt * NTILES_N;
    int m0  = mt * 128, n0 = nt * 128;

    {
        const u32x4* src = (const u32x4*)(Bw + (size_t)n0 * KB);
        u32x4* dst = (u32x4*)Bl;
        u32x4 stg[15];
        #pragma unroll
        for (int it = 0; it < 15; ++it) stg[it] = src[tid + it * 256];
        #pragma unroll
        for (int it = 0; it < 15; ++it) dst[tid + it * 256] = stg[it];
    }
    __syncthreads();

    int lane = tid & 63, wv = tid >> 6;
    int wr = wv >> 1, wc = wv & 1;
    int lr = lane & 15, lq = lane >> 4;
    f32x4 acc[4][4] = {};
    #pragma unroll
    for (int ks = 0; ks < 7; ++ks) {
        bf16x8 af[4], bfr[4];
        #pragma unroll
        for (int i = 0; i < 4; ++i) {
            int arow = m0 + wr * 64 + i * 16 + lr;
            af[i] = *(const bf16x8*)(A + (size_t)arow * KA + (ks * 4 + lq) * 8);
            int brow = wc * 64 + i * 16 + lr;
            bfr[i] = *(const bf16x8*)(Bl + brow * KB + (ks * 4 + lq) * 8);
        }
        #pragma unroll
        for (int i = 0; i < 4; ++i) {
            #pragma unroll
            for (int j = 0; j < 4; ++j) {
                acc[i][j] = __builtin_amdgcn_mfma_f32_16x16x32_bf16(af[i], bfr[j],
                                                                   acc[i][j], 0, 0, 0);
            }
        }
    }
    #pragma unroll
    for (int j = 0; j < 4; ++j) {
        int col = n0 + wc * 64 + j * 16 + lr;
        if (col < VOCAB) {
            float bias = fc_b[col];
            #pragma unroll
            for (int i = 0; i < 4; ++i) {
                #pragma unroll
                for (int r = 0; r < 4; ++r) {
                    int row = m0 + wr * 64 + i * 16 + lq * 4 + r;
                    Cout[(size_t)row * VOCAB + col] = acc[i][j][r] + bias;
                }
            }
        }
    }
}

extern "C" void kernel_launch(void* const* d_in, const int* in_sizes, int n_in,
                              void* d_out, int out_size, void* d_ws, size_t ws_size,
                              hipStream_t stream) {
    const int*   x    = (const int*)  d_in[0];
    const float* emb  = (const float*)d_in[1];
    const float* w_ih = (const float*)d_in[2];
    const float* w_hh = (const float*)d_in[3];
    const float* b_ih = (const float*)d_in[4];
    const float* b_hh = (const float*)d_in[5];
    const float* fc_w = (const float*)d_in[6];
    const float* fc_b = (const float*)d_in[7];
    float* out    = (float*)d_out;
    float* hidden = out + (size_t)M * VOCAB;

    char* ws = (char*)d_ws;
    float*    buf0 = (float*)(ws + OFF_BUF0);
    float*    buf1 = (float*)(ws + OFF_BUF1);
    float*    wt   = (float*)(ws + OFF_WT);
    __bf16*   hbf  = (__bf16*)(ws + OFF_HBF);
    __bf16*   fwb  = (__bf16*)(ws + OFF_FWB);
    unsigned* stg0 = (unsigned*)(ws + OFF_BUF0);   // aliases buf0 (post-k_xw)
    unsigned* stg1 = (unsigned*)(ws + OFF_STG1);

    k_embed <<<(M * D + 255) / 256, 256, 0, stream>>>(x, emb, buf0);
    k_wtrans<<<(NLAYERS * D * D + 255) / 256, 256, 0, stream>>>(w_ih, wt);
    k_fcwbf <<<(NPADA * KB + 255) / 256, 256, 0, stream>>>(fc_w, fwb);

    if (ws_size >= WS_NEED) {
        // pipelined path
        k_xw<<<M / 32, 256, 0, stream>>>(buf0, wt, b_ih, b_hh, buf1);  // layer 0
        const int nst4 = NB * NS * 200 / 4;            // 409,600 u32x4 cells
        const int nhb4 = M * KA * 2 / 16;              // hbf bytes/16
        k_zero<<<(nst4 + 255) / 256, 256, 0, stream>>>((u32x4*)stg0, nst4);
        k_zero<<<(nst4 + 255) / 256, 256, 0, stream>>>((u32x4*)stg1, nst4);
        k_zero<<<(nhb4 + 255) / 256, 256, 0, stream>>>((u32x4*)hbf, nhb4);
        k_scan_pipe<<<NB * NLAYERS, 512, 0, stream>>>(w_hh, w_ih, b_ih, b_hh,
                                                      buf1, stg0, stg1, hbf, hidden);
    } else {
        // fallback: r7-verified serial path
        float* cur = buf0;
        float* nxt = buf1;
        for (int l = 0; l < NLAYERS; ++l) {
            k_xw  <<<M / 32, 256, 0, stream>>>(cur, wt + l * D * D,
                                               b_ih + l * D, b_hh + l * D, nxt);
            k_scan<<<NB, 512, 0, stream>>>(w_hh + (size_t)l * D * D, nxt,
                                           hidden + l * NB * D);
            float* tswap = cur; cur = nxt; nxt = tswap;
        }
        k_hbf2<<<(M * KA + 255) / 256, 256, 0, stream>>>(cur, hbf);
    }
    k_fc<<<64 * NTILES_N, 256, 0, stream>>>(hbf, fwb, fc_b, out);
}